// Round 5
// baseline (415.436 us; speedup 1.0000x reference)
//
#include <hip/hip_runtime.h>
#include <cstdint>
#include <cstddef>

typedef unsigned int u32;
typedef unsigned short u16;
typedef float  f32x4 __attribute__((ext_vector_type(4)));
typedef short  s16x8 __attribute__((ext_vector_type(8)));
typedef unsigned short u16x4 __attribute__((ext_vector_type(4)));

typedef const __attribute__((address_space(1))) u32 gbl_u32;
typedef __attribute__((address_space(3))) u32 lds_u32;

#define FENCE asm volatile("" ::: "memory")

__device__ __forceinline__ u16 f2bf(float f) {          // RNE f32->bf16 (finite inputs)
    u32 u = __builtin_bit_cast(u32, f);
    u = (u + 0x7FFFu + ((u >> 16) & 1u)) >> 16;
    return (u16)u;
}

// ---------------- elementwise f32 -> bf16 convert ----------------
__global__ void k_cvt(const float* __restrict__ s, u16* __restrict__ d, int n4) {
    int i = blockIdx.x * 256 + threadIdx.x;
    if (i >= n4) return;
    float4 v = ((const float4*)s)[i];
    u16x4 o = { f2bf(v.x), f2bf(v.y), f2bf(v.z), f2bf(v.w) };
    *(u16x4*)(d + (size_t)i * 4) = o;
}

// ---------------- transpose + convert: src f32 [R][C] -> dst bf16 [C][R] ----------------
__global__ void k_tcvt(const float* __restrict__ s, u16* __restrict__ d, int R, int C) {
    __shared__ float t[32][33];
    int bx = blockIdx.x, by = blockIdx.y;
    int tx = threadIdx.x, ty = threadIdx.y;
    #pragma unroll
    for (int j = ty; j < 32; j += 8)
        t[j][tx] = s[(size_t)(by * 32 + j) * C + bx * 32 + tx];
    __syncthreads();
    #pragma unroll
    for (int j = ty; j < 32; j += 8)
        d[(size_t)(bx * 32 + j) * R + by * 32 + tx] = f2bf(t[tx][j]);
}

__global__ void k_zero(float* __restrict__ p, int n) {
    int i = blockIdx.x * 256 + threadIdx.x;
    if (i < n) p[i] = 0.f;
}

// final reduce: out = bias + sum over splitk partials   (2097152 f32 = 524288 float4)
__global__ void k_reduce(const float* __restrict__ part, const float* __restrict__ bias,
                         float* __restrict__ out, int splitk) {
    int i = blockIdx.x * 256 + threadIdx.x;          // float4 id
    float4 s = ((const float4*)bias)[i & 127];
    for (int j = 0; j < splitk; ++j) {
        float4 p = ((const float4*)part)[(size_t)j * 524288 + i];
        s.x += p.x; s.y += p.y; s.z += p.z; s.w += p.w;
    }
    ((float4*)out)[i] = s;
}

// ================= 256x256xK bf16 GEMM, B given transposed [N][K] ==================
// 8 waves (2x4). BK=32, 4-buffer LDS ring, prefetch depth 3, counted vmcnt(8),
// 2 phases x 16 MFMA per K-tile, swizzled LDS (slot ^= row&3), setprio on MFMA.
// ktiles counts 32-wide K-tiles.
// MODE 0: QKV projections (bz=mat)  MODE 1: P=exp(qk^T*scale)+rowsum-atomic
// MODE 2: O=(P v)/rowsum            MODE 3: split-K partials of Oattn@Wo
template<int MODE>
__global__ __launch_bounds__(512, 2) void k_gemm(
    const u16* __restrict__ Abase, const u16* __restrict__ Bbase,
    u16* __restrict__ out0, u16* __restrict__ out1, u16* __restrict__ out2,
    float* __restrict__ outf,
    const float* __restrict__ bias0, const float* __restrict__ bias1,
    const float* __restrict__ bias2,
    float* __restrict__ rsum, int bh_base, int ktiles)
{
    constexpr int LDA = (MODE == 2) ? 2048 : (MODE == 3) ? 4096 : 512;
    constexpr int LDB = (MODE == 2) ? 2048 : (MODE == 3) ? 4096 : 512;

    __shared__ u16 sh[65536];          // 4 bufs x (A 16KB + B 16KB) = 128 KiB

    const int tid = threadIdx.x;
    const int bx = blockIdx.x, by = blockIdx.y, bz = blockIdx.z;

    const u16* A; const u16* Bt;
    if constexpr (MODE == 0) {
        A  = Abase + (size_t)bz * 2097152 + (size_t)by * 256 * 512;
        Bt = Bbase + (size_t)bz * 2097152 + (size_t)bx * 256 * 512;
    } else if constexpr (MODE == 1) {
        int bh = bh_base + bz;
        A  = Abase + (size_t)bh * 1048576 + (size_t)by * 256 * 512;
        Bt = Bbase + (size_t)bh * 1048576 + (size_t)bx * 256 * 512;
    } else if constexpr (MODE == 2) {
        int bh = bh_base + bz;
        A  = Abase + (size_t)bz * 4194304 + (size_t)by * 256 * 2048;
        Bt = Bbase + (size_t)bh * 1048576 + (size_t)bx * 256 * 2048;
    } else {
        A  = Abase + (size_t)by * 256 * 4096 + (size_t)bz * (ktiles * 32);
        Bt = Bbase + (size_t)bx * 256 * 4096 + (size_t)bz * (ktiles * 32);
    }

    // ---- staging: one K-tile = A(256x32) + B(256x32) bf16; 4 loads/thread total.
    // LDS dest linear (wave-uniform base + lane*16); global source inverse-swizzled
    // (16B slot s at row r holds logical slot s^(r&3)).
    char* shb = (char*)&sh[0];
    auto stageA = [&](int kt) {
        const int koff = kt * 32, b = kt & 3;
        #pragma unroll
        for (int r = 0; r < 2; ++r) {
            const int la  = (r * 512 + tid) * 16;            // linear byte in 16KB region
            const int row = la >> 6;                          // 0..255
            const int cb  = (la & 63) ^ ((row & 3) << 4);     // logical byte-in-row
            const u16* ga = A + (size_t)row * LDA + koff + (cb >> 1);
            lds_u32* dst = (lds_u32*)(shb + b * 32768 + r * 8192 + ((tid >> 6) << 10));
            __builtin_amdgcn_global_load_lds((gbl_u32*)ga, dst, 16, 0, 0);
        }
    };
    auto stageB = [&](int kt) {
        const int koff = kt * 32, b = kt & 3;
        #pragma unroll
        for (int r = 0; r < 2; ++r) {
            const int la  = (r * 512 + tid) * 16;
            const int row = la >> 6;
            const int cb  = (la & 63) ^ ((row & 3) << 4);
            const u16* gb = Bt + (size_t)row * LDB + koff + (cb >> 1);
            lds_u32* dst = (lds_u32*)(shb + b * 32768 + 16384 + r * 8192 + ((tid >> 6) << 10));
            __builtin_amdgcn_global_load_lds((gbl_u32*)gb, dst, 16, 0, 0);
        }
    };

    const int l  = tid & 63, w = tid >> 6;
    const int wm = (w >> 2) * 128, wn = (w & 3) * 64;        // wave tile origin
    const int lg = l >> 4, lr = l & 15;
    const int slotb = ((lg ^ (lr & 3)) << 4);                // swizzled 16B slot in 64B row

    auto rdA = [&](int b, int m) -> s16x8 {
        const int row = wm + m * 16 + lr;
        return *(const s16x8*)(shb + b * 32768 + row * 64 + slotb);
    };
    auto rdB = [&](int b, int n) -> s16x8 {
        const int row = wn + n * 16 + lr;
        return *(const s16x8*)(shb + b * 32768 + 16384 + row * 64 + slotb);
    };

    f32x4 acc[8][4];
    #pragma unroll
    for (int m = 0; m < 8; ++m)
        #pragma unroll
        for (int n = 0; n < 4; ++n)
            #pragma unroll
            for (int r = 0; r < 4; ++r) acc[m][n][r] = 0.f;

    const int n_t = ktiles;
    stageA(0); stageB(0);
    stageA(1); stageB(1);
    stageA(2); stageB(2);                                    // 12 loads in flight

    for (int t = 0; t < n_t; ++t) {
        const int b = t & 3;
        const int rem = n_t - 1 - t;
        if (rem >= 2)      asm volatile("s_waitcnt vmcnt(8)" ::: "memory");
        else if (rem == 1) asm volatile("s_waitcnt vmcnt(4)" ::: "memory");
        else               asm volatile("s_waitcnt vmcnt(0)" ::: "memory");
        __builtin_amdgcn_sched_barrier(0);
        FENCE; __builtin_amdgcn_s_barrier(); FENCE;          // tile t resident, buf t-1 reads done

        // ---- phase 0: frags for m0-3 x n0-3, stage A-half of t+3
        s16x8 a0[4], bv[4], a1[4];
        #pragma unroll
        for (int m = 0; m < 4; ++m) a0[m] = rdA(b, m);
        #pragma unroll
        for (int n = 0; n < 4; ++n) bv[n] = rdB(b, n);
        if (t + 3 < n_t) stageA(t + 3);
        FENCE; __builtin_amdgcn_s_barrier(); FENCE;
        asm volatile("s_waitcnt lgkmcnt(0)" ::: "memory");
        __builtin_amdgcn_sched_barrier(0);
        __builtin_amdgcn_s_setprio(1);
        #pragma unroll
        for (int m = 0; m < 4; ++m)
            #pragma unroll
            for (int n = 0; n < 4; ++n)
                acc[m][n] = __builtin_amdgcn_mfma_f32_16x16x32_bf16(a0[m], bv[n], acc[m][n], 0, 0, 0);
        __builtin_amdgcn_s_setprio(0);
        FENCE; __builtin_amdgcn_s_barrier(); FENCE;

        // ---- phase 1: frags for m4-7 (reuse bv), stage B-half of t+3
        #pragma unroll
        for (int m = 0; m < 4; ++m) a1[m] = rdA(b, m + 4);
        if (t + 3 < n_t) stageB(t + 3);
        FENCE; __builtin_amdgcn_s_barrier(); FENCE;
        asm volatile("s_waitcnt lgkmcnt(0)" ::: "memory");
        __builtin_amdgcn_sched_barrier(0);
        __builtin_amdgcn_s_setprio(1);
        #pragma unroll
        for (int m = 0; m < 4; ++m)
            #pragma unroll
            for (int n = 0; n < 4; ++n)
                acc[m + 4][n] = __builtin_amdgcn_mfma_f32_16x16x32_bf16(a1[m], bv[n], acc[m + 4][n], 0, 0, 0);
        __builtin_amdgcn_s_setprio(0);
        // next iteration's entry barrier closes this phase
    }

    // ---------------- epilogue: C/D col = lr, row = lg*4 + r  [m89 verified] ----------------
    if constexpr (MODE == 0) {
        const float* bias = (bz == 0) ? bias0 : ((bz == 1) ? bias1 : bias2);
        #pragma unroll
        for (int m = 0; m < 8; ++m)
        #pragma unroll
        for (int n = 0; n < 4; ++n)
        #pragma unroll
        for (int r = 0; r < 4; ++r) {
            const int grow = by * 256 + wm + m * 16 + lg * 4 + r;   // b*2048+s
            const int gcol = bx * 256 + wn + n * 16 + lr;           // h*512+d
            const u16 o = f2bf(acc[m][n][r] + bias[gcol]);
            const int bb = grow >> 11, ss = grow & 2047;
            const int hh = gcol >> 9,  dd = gcol & 511;
            if (bz == 0)      out0[(((size_t)(bb * 8 + hh) * 2048 + ss) << 9)  + dd] = o;
            else if (bz == 1) out1[(((size_t)(bb * 8 + hh) * 2048 + ss) << 9)  + dd] = o;
            else              out2[(((size_t)(bb * 8 + hh) * 512  + dd) << 11) + ss] = o; // v^T
        }
    } else if constexpr (MODE == 1) {
        const int bh = bh_base + bz;
        u16* Pp = out0 + (size_t)bz * 4194304;
        #pragma unroll
        for (int m = 0; m < 8; ++m)
        #pragma unroll
        for (int r = 0; r < 4; ++r) {
            const int grow = by * 256 + wm + m * 16 + lg * 4 + r;
            float rs = 0.f;
            #pragma unroll
            for (int n = 0; n < 4; ++n) {
                const int gcol = bx * 256 + wn + n * 16 + lr;
                float p = __expf(acc[m][n][r] * 0.04419417382415922f);  // 1/sqrt(512)
                rs += p;
                Pp[((size_t)grow << 11) + gcol] = f2bf(p);
            }
            #pragma unroll
            for (int o = 1; o < 16; o <<= 1) rs += __shfl_xor(rs, o, 64);
            if (lr == 0) atomicAdd(&rsum[bh * 2048 + grow], rs);
        }
    } else if constexpr (MODE == 2) {
        const int bh = bh_base + bz;
        const int bb = bh >> 3, hh = bh & 7;
        #pragma unroll
        for (int m = 0; m < 8; ++m)
        #pragma unroll
        for (int r = 0; r < 4; ++r) {
            const int grow = by * 256 + wm + m * 16 + lg * 4 + r;
            const float ri = 1.0f / rsum[bh * 2048 + grow];
            #pragma unroll
            for (int n = 0; n < 4; ++n) {
                const int gcol = bx * 256 + wn + n * 16 + lr;           // 0..511
                out0[((size_t)(bb * 2048 + grow) << 12) + hh * 512 + gcol] = f2bf(acc[m][n][r] * ri);
            }
        }
    } else {
        #pragma unroll
        for (int m = 0; m < 8; ++m)
        #pragma unroll
        for (int n = 0; n < 4; ++n)
        #pragma unroll
        for (int r = 0; r < 4; ++r) {
            const int grow = by * 256 + wm + m * 16 + lg * 4 + r;       // 0..4095
            const int gcol = bx * 256 + wn + n * 16 + lr;               // 0..511
            outf[(size_t)bz * 2097152 + (size_t)grow * 512 + gcol] = acc[m][n][r];
        }
    }
}

extern "C" void kernel_launch(void* const* d_in, const int* in_sizes, int n_in,
                              void* d_out, int out_size, void* d_ws, size_t ws_size,
                              hipStream_t stream) {
    const float* Q  = (const float*)d_in[0];
    const float* K  = (const float*)d_in[1];
    const float* V  = (const float*)d_in[2];
    const float* bq = (const float*)d_in[4];
    const float* bk = (const float*)d_in[6];
    const float* bv = (const float*)d_in[8];
    const float* bo = (const float*)d_in[10];
    const float* Wq = (const float*)d_in[3];
    const float* Wk = (const float*)d_in[5];
    const float* Wv = (const float*)d_in[7];
    const float* Wo = (const float*)d_in[9];
    float* out = (float*)d_out;

    char* ws = (char*)d_ws;
    u16*   qkvbf = (u16*)  (ws + 0);            // [3][4096][512] bf16
    u16*   Wt    = (u16*)  (ws + 12582912);     // Wq^T,Wk^T,Wv^T [3][4096][512]
    u16*   WoT   = (u16*)  (ws + 25165824);     // Wo^T [512][4096]
    float* rsum  = (float*)(ws + 29360128);     // [16][2048]
    u16*   qproj = (u16*)  (ws + 29491200);     // [B,H,S,512]
    u16*   kproj = (u16*)  (ws + 63045632);     // [B,H,S,512]
    u16*   vT    = (u16*)  (ws + 96600064);     // [B,H,512,S]
    u16*   Oattn = (u16*)  (ws + 130154496);    // [B*S][4096]
    u16*   P     = (u16*)  (ws + 163708928);    // chunked [ch][2048][2048]
    float* part  = (float*)(ws + 163708928);    // reused: [splitk][4096][512] f32

    size_t avail = (ws_size > (size_t)163708928) ? ws_size - (size_t)163708928 : 0;
    int hp = (int)(avail / 8388608);
    if (hp < 1)  hp = 1;
    if (hp > 16) hp = 16;
    int splitk = (hp >= 8) ? 8 : (hp >= 4) ? 4 : (hp >= 2) ? 2 : 1;

    // input converts
    k_cvt<<<2048, 256, 0, stream>>>(Q, qkvbf,            524288);
    k_cvt<<<2048, 256, 0, stream>>>(K, qkvbf + 2097152,  524288);
    k_cvt<<<2048, 256, 0, stream>>>(V, qkvbf + 4194304,  524288);
    dim3 tb(32, 8);
    k_tcvt<<<dim3(128, 16), tb, 0, stream>>>(Wq, Wt,            512, 4096);
    k_tcvt<<<dim3(128, 16), tb, 0, stream>>>(Wk, Wt + 2097152,  512, 4096);
    k_tcvt<<<dim3(128, 16), tb, 0, stream>>>(Wv, Wt + 4194304,  512, 4096);
    k_tcvt<<<dim3(16, 128), tb, 0, stream>>>(Wo, WoT,           4096, 512);
    k_zero<<<128, 256, 0, stream>>>(rsum, 32768);

    // fused QKV projections (+bias): q,k -> [B,H,S,D], v -> [B,H,D,S]
    k_gemm<0><<<dim3(16, 16, 3), 512, 0, stream>>>(qkvbf, Wt, qproj, kproj, vT, nullptr,
                                                   bq, bk, bv, nullptr, 0, 16);

    // attention: P = exp(qk^T*scale) with fused row-sums; O = P v / rowsum
    for (int h0 = 0; h0 < 16; h0 += hp) {
        int ch = (16 - h0 < hp) ? (16 - h0) : hp;
        k_gemm<1><<<dim3(8, 8, ch), 512, 0, stream>>>(qproj, kproj, P, nullptr, nullptr,
                                                      nullptr, nullptr, nullptr, nullptr,
                                                      rsum, h0, 16);
        k_gemm<2><<<dim3(2, 8, ch), 512, 0, stream>>>(P, vT, Oattn, nullptr, nullptr,
                                                      nullptr, nullptr, nullptr, nullptr,
                                                      rsum, h0, 64);
    }

    // final projection: split-K partials + reduce(+bias) -> f32 out
    k_gemm<3><<<dim3(2, 16, splitk), 512, 0, stream>>>(Oattn, WoT, nullptr, nullptr, nullptr,
                                                       part, nullptr, nullptr, nullptr,
                                                       nullptr, 0, 128 / splitk);
    k_reduce<<<2048, 256, 0, stream>>>(part, bo, out, splitk);
}

// Round 6
// 389.318 us; speedup vs baseline: 1.0671x; 1.0671x over previous
//
#include <hip/hip_runtime.h>
#include <cstdint>
#include <cstddef>

typedef unsigned int u32;
typedef unsigned short u16;
typedef float  f32x4 __attribute__((ext_vector_type(4)));
typedef short  s16x8 __attribute__((ext_vector_type(8)));
typedef unsigned short u16x4 __attribute__((ext_vector_type(4)));

typedef const __attribute__((address_space(1))) u32 gbl_u32;
typedef __attribute__((address_space(3))) u32 lds_u32;

#define FENCE asm volatile("" ::: "memory")

__device__ __forceinline__ u16 f2bf(float f) {          // RNE f32->bf16 (finite inputs)
    u32 u = __builtin_bit_cast(u32, f);
    u = (u + 0x7FFFu + ((u >> 16) & 1u)) >> 16;
    return (u16)u;
}

// ---------------- elementwise f32 -> bf16 convert ----------------
__global__ void k_cvt(const float* __restrict__ s, u16* __restrict__ d, int n4) {
    int i = blockIdx.x * 256 + threadIdx.x;
    if (i >= n4) return;
    float4 v = ((const float4*)s)[i];
    u16x4 o = { f2bf(v.x), f2bf(v.y), f2bf(v.z), f2bf(v.w) };
    *(u16x4*)(d + (size_t)i * 4) = o;
}

// ---------------- transpose + convert: src f32 [R][C] -> dst bf16 [C][R] ----------------
__global__ void k_tcvt(const float* __restrict__ s, u16* __restrict__ d, int R, int C) {
    __shared__ float t[32][33];
    int bx = blockIdx.x, by = blockIdx.y;
    int tx = threadIdx.x, ty = threadIdx.y;
    #pragma unroll
    for (int j = ty; j < 32; j += 8)
        t[j][tx] = s[(size_t)(by * 32 + j) * C + bx * 32 + tx];
    __syncthreads();
    #pragma unroll
    for (int j = ty; j < 32; j += 8)
        d[(size_t)(bx * 32 + j) * R + by * 32 + tx] = f2bf(t[tx][j]);
}

__global__ void k_zero(float* __restrict__ p, int n) {
    int i = blockIdx.x * 256 + threadIdx.x;
    if (i < n) p[i] = 0.f;
}

// final reduce: out = bias + sum over splitk partials   (2097152 f32 = 524288 float4)
__global__ void k_reduce(const float* __restrict__ part, const float* __restrict__ bias,
                         float* __restrict__ out, int splitk) {
    int i = blockIdx.x * 256 + threadIdx.x;          // float4 id
    float4 s = ((const float4*)bias)[i & 127];
    for (int j = 0; j < splitk; ++j) {
        float4 p = ((const float4*)part)[(size_t)j * 524288 + i];
        s.x += p.x; s.y += p.y; s.z += p.z; s.w += p.w;
    }
    ((float4*)out)[i] = s;
}

// ================= 256x256xK bf16 GEMM, B given transposed [N][K] ==================
// 8 waves (2x4), BK=64, double-buffered LDS, counted vmcnt(8), XOR-swizzled LDS
// (proven 0-conflict), 4 phases x 16 MFMA per K-tile (m201-style fine interleave).
// MODE 0: QKV projections (bz=mat)  MODE 1: P=exp(qk^T*scale)+rowsum-atomic
// MODE 2: O=(P v)/rowsum            MODE 3: split-K partials of Oattn@Wo
template<int MODE>
__global__ __launch_bounds__(512, 2) void k_gemm(
    const u16* __restrict__ Abase, const u16* __restrict__ Bbase,
    u16* __restrict__ out0, u16* __restrict__ out1, u16* __restrict__ out2,
    float* __restrict__ outf,
    const float* __restrict__ bias0, const float* __restrict__ bias1,
    const float* __restrict__ bias2,
    float* __restrict__ rsum, int bh_base, int ktiles)
{
    constexpr int LDA = (MODE == 2) ? 2048 : (MODE == 3) ? 4096 : 512;
    constexpr int LDB = (MODE == 2) ? 2048 : (MODE == 3) ? 4096 : 512;

    __shared__ u16 lds[2][2][16384];   // [buf][A/B][256 rows x 64 k] = 128 KiB

    const int tid = threadIdx.x;
    const int bx = blockIdx.x, by = blockIdx.y, bz = blockIdx.z;

    const u16* A; const u16* Bt;
    if constexpr (MODE == 0) {
        A  = Abase + (size_t)bz * 2097152 + (size_t)by * 256 * 512;
        Bt = Bbase + (size_t)bz * 2097152 + (size_t)bx * 256 * 512;
    } else if constexpr (MODE == 1) {
        int bh = bh_base + bz;
        A  = Abase + (size_t)bh * 1048576 + (size_t)by * 256 * 512;
        Bt = Bbase + (size_t)bh * 1048576 + (size_t)bx * 256 * 512;
    } else if constexpr (MODE == 2) {
        int bh = bh_base + bz;
        A  = Abase + (size_t)bz * 4194304 + (size_t)by * 256 * 2048;
        Bt = Bbase + (size_t)bh * 1048576 + (size_t)bx * 256 * 2048;
    } else {
        A  = Abase + (size_t)by * 256 * 4096 + (size_t)bz * (ktiles * 64);
        Bt = Bbase + (size_t)bx * 256 * 4096 + (size_t)bz * (ktiles * 64);
    }

    // stage K-tile kt into buffer b: linear LDS dest, inverse-swizzled global source
    auto stage = [&](int kt, int b) {
        const int koff = kt * 64;
        #pragma unroll
        for (int r = 0; r < 4; ++r) {
            const int a   = (r * 512 + tid) * 16;            // linear byte in 32KB region
            const int row = a >> 7;                          // 0..255
            const int cb  = (a & 127) ^ ((row & 7) << 4);    // logical byte-in-row
            const u16* ga = A  + (size_t)row * LDA + koff + (cb >> 1);
            const u16* gb = Bt + (size_t)row * LDB + koff + (cb >> 1);
            lds_u32* la = (lds_u32*)((char*)&lds[b][0][0] + r * 8192 + ((tid >> 6) << 10));
            lds_u32* lb = (lds_u32*)((char*)&lds[b][1][0] + r * 8192 + ((tid >> 6) << 10));
            __builtin_amdgcn_global_load_lds((gbl_u32*)ga, la, 16, 0, 0);
            __builtin_amdgcn_global_load_lds((gbl_u32*)gb, lb, 16, 0, 0);
        }
    };

    const int l  = tid & 63, w = tid >> 6;
    const int wm = (w >> 2) * 128, wn = (w & 3) * 64;        // wave tile origin
    const int lg = l >> 4, lr = l & 15;
    const int swz = (lr & 7) << 4;

    // swizzled fragment reads (16x16x32: lane holds row lr, k-slot group lg)
    auto rdA = [&](int b, int m, int s) -> s16x8 {
        const int row = wm + m * 16 + lr;
        return *(const s16x8*)((const char*)&lds[b][0][0] + row * 128 + ((s * 64 + lg * 16) ^ swz));
    };
    auto rdB = [&](int b, int n, int s) -> s16x8 {
        const int row = wn + n * 16 + lr;
        return *(const s16x8*)((const char*)&lds[b][1][0] + row * 128 + ((s * 64 + lg * 16) ^ swz));
    };

    f32x4 acc[8][4];
    #pragma unroll
    for (int m = 0; m < 8; ++m)
        #pragma unroll
        for (int n = 0; n < 4; ++n)
            #pragma unroll
            for (int r = 0; r < 4; ++r) acc[m][n][r] = 0.f;

    stage(0, 0);
    if (ktiles > 1) stage(1, 1);

    for (int t = 0; t < ktiles; ++t) {
        const int b = t & 1;
        if (t + 1 < ktiles) { asm volatile("s_waitcnt vmcnt(8)" ::: "memory"); }
        else               { asm volatile("s_waitcnt vmcnt(0)" ::: "memory"); }
        __builtin_amdgcn_sched_barrier(0);
        FENCE; __builtin_amdgcn_s_barrier(); FENCE;          // tile t resident

        s16x8 aL[8], aH[8], bv[8];                           // A m0-3, A m4-7, B n0-3 (x ks0-1)

        // ---- phase 0: read A m0-3 (8) + B n0-1 (4); MFMA m0-3 x n0-1
        #pragma unroll
        for (int i = 0; i < 8; ++i) aL[i] = rdA(b, i >> 1, i & 1);
        #pragma unroll
        for (int i = 0; i < 4; ++i) bv[i] = rdB(b, i >> 1, i & 1);
        FENCE; __builtin_amdgcn_s_barrier(); FENCE;
        asm volatile("s_waitcnt lgkmcnt(0)" ::: "memory");
        __builtin_amdgcn_sched_barrier(0);
        __builtin_amdgcn_s_setprio(1);
        #pragma unroll
        for (int m = 0; m < 4; ++m)
            #pragma unroll
            for (int n = 0; n < 2; ++n)
                #pragma unroll
                for (int ks = 0; ks < 2; ++ks)
                    acc[m][n] = __builtin_amdgcn_mfma_f32_16x16x32_bf16(aL[m*2+ks], bv[n*2+ks], acc[m][n], 0, 0, 0);
        __builtin_amdgcn_s_setprio(0);
        FENCE; __builtin_amdgcn_s_barrier(); FENCE;

        // ---- phase 1: read B n2-3 (4); MFMA m0-3 x n2-3
        #pragma unroll
        for (int i = 4; i < 8; ++i) bv[i] = rdB(b, i >> 1, i & 1);
        FENCE; __builtin_amdgcn_s_barrier(); FENCE;
        asm volatile("s_waitcnt lgkmcnt(0)" ::: "memory");
        __builtin_amdgcn_sched_barrier(0);
        __builtin_amdgcn_s_setprio(1);
        #pragma unroll
        for (int m = 0; m < 4; ++m)
            #pragma unroll
            for (int n = 2; n < 4; ++n)
                #pragma unroll
                for (int ks = 0; ks < 2; ++ks)
                    acc[m][n] = __builtin_amdgcn_mfma_f32_16x16x32_bf16(aL[m*2+ks], bv[n*2+ks], acc[m][n], 0, 0, 0);
        __builtin_amdgcn_s_setprio(0);
        FENCE; __builtin_amdgcn_s_barrier(); FENCE;

        // ---- phase 2: read A m4-7 (8); MFMA m4-7 x n2-3
        #pragma unroll
        for (int i = 0; i < 8; ++i) aH[i] = rdA(b, 4 + (i >> 1), i & 1);
        FENCE; __builtin_amdgcn_s_barrier(); FENCE;
        asm volatile("s_waitcnt lgkmcnt(0)" ::: "memory");
        __builtin_amdgcn_sched_barrier(0);
        __builtin_amdgcn_s_setprio(1);
        #pragma unroll
        for (int m = 0; m < 4; ++m)
            #pragma unroll
            for (int n = 2; n < 4; ++n)
                #pragma unroll
                for (int ks = 0; ks < 2; ++ks)
                    acc[m+4][n] = __builtin_amdgcn_mfma_f32_16x16x32_bf16(aH[m*2+ks], bv[n*2+ks], acc[m+4][n], 0, 0, 0);
        __builtin_amdgcn_s_setprio(0);
        FENCE; __builtin_amdgcn_s_barrier(); FENCE;          // all reads of buf b complete

        // ---- phase 3: stage t+2 into buf b (safe now); MFMA m4-7 x n0-1 (regs only)
        if (t + 2 < ktiles) stage(t + 2, b);
        __builtin_amdgcn_s_setprio(1);
        #pragma unroll
        for (int m = 0; m < 4; ++m)
            #pragma unroll
            for (int n = 0; n < 2; ++n)
                #pragma unroll
                for (int ks = 0; ks < 2; ++ks)
                    acc[m+4][n] = __builtin_amdgcn_mfma_f32_16x16x32_bf16(aH[m*2+ks], bv[n*2+ks], acc[m+4][n], 0, 0, 0);
        __builtin_amdgcn_s_setprio(0);
        // next iteration's entry barrier closes this phase
    }

    // ---------------- epilogue: C/D col = lr, row = lg*4 + r  [m89 verified] ----------------
    if constexpr (MODE == 0) {
        const float* bias = (bz == 0) ? bias0 : ((bz == 1) ? bias1 : bias2);
        #pragma unroll
        for (int m = 0; m < 8; ++m)
        #pragma unroll
        for (int n = 0; n < 4; ++n)
        #pragma unroll
        for (int r = 0; r < 4; ++r) {
            const int grow = by * 256 + wm + m * 16 + lg * 4 + r;   // b*2048+s
            const int gcol = bx * 256 + wn + n * 16 + lr;           // h*512+d
            const u16 o = f2bf(acc[m][n][r] + bias[gcol]);
            const int bb = grow >> 11, ss = grow & 2047;
            const int hh = gcol >> 9,  dd = gcol & 511;
            if (bz == 0)      out0[(((size_t)(bb * 8 + hh) * 2048 + ss) << 9)  + dd] = o;
            else if (bz == 1) out1[(((size_t)(bb * 8 + hh) * 2048 + ss) << 9)  + dd] = o;
            else              out2[(((size_t)(bb * 8 + hh) * 512  + dd) << 11) + ss] = o; // v^T
        }
    } else if constexpr (MODE == 1) {
        const int bh = bh_base + bz;
        u16* Pp = out0 + (size_t)bz * 4194304;
        #pragma unroll
        for (int m = 0; m < 8; ++m)
        #pragma unroll
        for (int r = 0; r < 4; ++r) {
            const int grow = by * 256 + wm + m * 16 + lg * 4 + r;
            float rs = 0.f;
            #pragma unroll
            for (int n = 0; n < 4; ++n) {
                const int gcol = bx * 256 + wn + n * 16 + lr;
                float p = __expf(acc[m][n][r] * 0.04419417382415922f);  // 1/sqrt(512)
                rs += p;
                Pp[((size_t)grow << 11) + gcol] = f2bf(p);
            }
            #pragma unroll
            for (int o = 1; o < 16; o <<= 1) rs += __shfl_xor(rs, o, 64);
            if (lr == 0) atomicAdd(&rsum[bh * 2048 + grow], rs);
        }
    } else if constexpr (MODE == 2) {
        const int bh = bh_base + bz;
        const int bb = bh >> 3, hh = bh & 7;
        #pragma unroll
        for (int m = 0; m < 8; ++m)
        #pragma unroll
        for (int r = 0; r < 4; ++r) {
            const int grow = by * 256 + wm + m * 16 + lg * 4 + r;
            const float ri = 1.0f / rsum[bh * 2048 + grow];
            #pragma unroll
            for (int n = 0; n < 4; ++n) {
                const int gcol = bx * 256 + wn + n * 16 + lr;           // 0..511
                out0[((size_t)(bb * 2048 + grow) << 12) + hh * 512 + gcol] = f2bf(acc[m][n][r] * ri);
            }
        }
    } else {
        #pragma unroll
        for (int m = 0; m < 8; ++m)
        #pragma unroll
        for (int n = 0; n < 4; ++n)
        #pragma unroll
        for (int r = 0; r < 4; ++r) {
            const int grow = by * 256 + wm + m * 16 + lg * 4 + r;       // 0..4095
            const int gcol = bx * 256 + wn + n * 16 + lr;               // 0..511
            outf[(size_t)bz * 2097152 + (size_t)grow * 512 + gcol] = acc[m][n][r];
        }
    }
}

extern "C" void kernel_launch(void* const* d_in, const int* in_sizes, int n_in,
                              void* d_out, int out_size, void* d_ws, size_t ws_size,
                              hipStream_t stream) {
    const float* Q  = (const float*)d_in[0];
    const float* K  = (const float*)d_in[1];
    const float* V  = (const float*)d_in[2];
    const float* bq = (const float*)d_in[4];
    const float* bk = (const float*)d_in[6];
    const float* bv = (const float*)d_in[8];
    const float* bo = (const float*)d_in[10];
    const float* Wq = (const float*)d_in[3];
    const float* Wk = (const float*)d_in[5];
    const float* Wv = (const float*)d_in[7];
    const float* Wo = (const float*)d_in[9];
    float* out = (float*)d_out;

    char* ws = (char*)d_ws;
    u16*   qkvbf = (u16*)  (ws + 0);            // [3][4096][512] bf16
    u16*   Wt    = (u16*)  (ws + 12582912);     // Wq^T,Wk^T,Wv^T [3][4096][512]
    u16*   WoT   = (u16*)  (ws + 25165824);     // Wo^T [512][4096]
    float* rsum  = (float*)(ws + 29360128);     // [16][2048]
    u16*   qproj = (u16*)  (ws + 29491200);     // [B,H,S,512]
    u16*   kproj = (u16*)  (ws + 63045632);     // [B,H,S,512]
    u16*   vT    = (u16*)  (ws + 96600064);     // [B,H,512,S]
    u16*   Oattn = (u16*)  (ws + 130154496);    // [B*S][4096]
    u16*   P     = (u16*)  (ws + 163708928);    // chunked [ch][2048][2048]
    float* part  = (float*)(ws + 163708928);    // reused: [splitk][4096][512] f32

    size_t avail = (ws_size > (size_t)163708928) ? ws_size - (size_t)163708928 : 0;
    int hp = (int)(avail / 8388608);
    if (hp < 1)  hp = 1;
    if (hp > 16) hp = 16;
    int splitk = (hp >= 8) ? 8 : (hp >= 4) ? 4 : (hp >= 2) ? 2 : 1;

    // input converts
    k_cvt<<<2048, 256, 0, stream>>>(Q, qkvbf,            524288);
    k_cvt<<<2048, 256, 0, stream>>>(K, qkvbf + 2097152,  524288);
    k_cvt<<<2048, 256, 0, stream>>>(V, qkvbf + 4194304,  524288);
    dim3 tb(32, 8);
    k_tcvt<<<dim3(128, 16), tb, 0, stream>>>(Wq, Wt,            512, 4096);
    k_tcvt<<<dim3(128, 16), tb, 0, stream>>>(Wk, Wt + 2097152,  512, 4096);
    k_tcvt<<<dim3(128, 16), tb, 0, stream>>>(Wv, Wt + 4194304,  512, 4096);
    k_tcvt<<<dim3(16, 128), tb, 0, stream>>>(Wo, WoT,           4096, 512);
    k_zero<<<128, 256, 0, stream>>>(rsum, 32768);

    // fused QKV projections (+bias): q,k -> [B,H,S,D], v -> [B,H,D,S]
    k_gemm<0><<<dim3(16, 16, 3), 512, 0, stream>>>(qkvbf, Wt, qproj, kproj, vT, nullptr,
                                                   bq, bk, bv, nullptr, 0, 8);

    // attention: P = exp(qk^T*scale) with fused row-sums; O = P v / rowsum
    for (int h0 = 0; h0 < 16; h0 += hp) {
        int ch = (16 - h0 < hp) ? (16 - h0) : hp;
        k_gemm<1><<<dim3(8, 8, ch), 512, 0, stream>>>(qproj, kproj, P, nullptr, nullptr,
                                                      nullptr, nullptr, nullptr, nullptr,
                                                      rsum, h0, 8);
        k_gemm<2><<<dim3(2, 8, ch), 512, 0, stream>>>(P, vT, Oattn, nullptr, nullptr,
                                                      nullptr, nullptr, nullptr, nullptr,
                                                      rsum, h0, 32);
    }

    // final projection: split-K partials + reduce(+bias) -> f32 out
    k_gemm<3><<<dim3(2, 16, splitk), 512, 0, stream>>>(Oattn, WoT, nullptr, nullptr, nullptr,
                                                       part, nullptr, nullptr, nullptr,
                                                       nullptr, 0, 64 / splitk);
    k_reduce<<<2048, 256, 0, stream>>>(part, bo, out, splitk);
}

// Round 7
// 363.393 us; speedup vs baseline: 1.1432x; 1.0713x over previous
//
#include <hip/hip_runtime.h>
#include <cstdint>
#include <cstddef>

typedef unsigned int u32;
typedef unsigned short u16;
typedef float  f32x4 __attribute__((ext_vector_type(4)));
typedef short  s16x8 __attribute__((ext_vector_type(8)));
typedef unsigned short u16x4 __attribute__((ext_vector_type(4)));

typedef const __attribute__((address_space(1))) u32 gbl_u32;
typedef __attribute__((address_space(3))) u32 lds_u32;

__device__ __forceinline__ u16 f2bf(float f) {          // RNE f32->bf16 (finite inputs)
    u32 u = __builtin_bit_cast(u32, f);
    u = (u + 0x7FFFu + ((u >> 16) & 1u)) >> 16;
    return (u16)u;
}

// ---------------- elementwise f32 -> bf16 convert ----------------
__global__ void k_cvt(const float* __restrict__ s, u16* __restrict__ d, int n4) {
    int i = blockIdx.x * 256 + threadIdx.x;
    if (i >= n4) return;
    float4 v = ((const float4*)s)[i];
    u16x4 o = { f2bf(v.x), f2bf(v.y), f2bf(v.z), f2bf(v.w) };
    *(u16x4*)(d + (size_t)i * 4) = o;
}

// ---------------- transpose + convert: src f32 [R][C] -> dst bf16 [C][R] ----------------
__global__ void k_tcvt(const float* __restrict__ s, u16* __restrict__ d, int R, int C) {
    __shared__ float t[32][33];
    int bx = blockIdx.x, by = blockIdx.y;
    int tx = threadIdx.x, ty = threadIdx.y;
    #pragma unroll
    for (int j = ty; j < 32; j += 8)
        t[j][tx] = s[(size_t)(by * 32 + j) * C + bx * 32 + tx];
    __syncthreads();
    #pragma unroll
    for (int j = ty; j < 32; j += 8)
        d[(size_t)(bx * 32 + j) * R + by * 32 + tx] = f2bf(t[tx][j]);
}

__global__ void k_zero(float* __restrict__ p, int n) {
    int i = blockIdx.x * 256 + threadIdx.x;
    if (i < n) p[i] = 0.f;
}

// final reduce: out = bias + sum over splitk partials   (2097152 f32 = 524288 float4)
__global__ void k_reduce(const float* __restrict__ part, const float* __restrict__ bias,
                         float* __restrict__ out, int splitk) {
    int i = blockIdx.x * 256 + threadIdx.x;          // float4 id
    float4 s = ((const float4*)bias)[i & 127];
    for (int j = 0; j < splitk; ++j) {
        float4 p = ((const float4*)part)[(size_t)j * 524288 + i];
        s.x += p.x; s.y += p.y; s.z += p.z; s.w += p.w;
    }
    ((float4*)out)[i] = s;
}

// ================= 128x128xK bf16 GEMM, B given transposed [N][K] ==================
// m97-structure: 4 waves (2x2), BK=64, SINGLE-buffered 32 KiB LDS, plain
// __syncthreads 2-barrier loop; 3 blocks/CU co-resident provide the overlap
// (m114 implicit cross-block pipelining). XOR-swizzled LDS (0-conflict verified),
// global_load_lds width 16.
// MODE 0: QKV projections (bz=mat)  MODE 1: P=exp(qk^T*scale)+rowsum-atomic
// MODE 2: O=(P v)/rowsum            MODE 3: split-K partials of Oattn@Wo
template<int MODE>
__global__ __launch_bounds__(256, 3) void k_gemm(
    const u16* __restrict__ Abase, const u16* __restrict__ Bbase,
    u16* __restrict__ out0, u16* __restrict__ out1, u16* __restrict__ out2,
    float* __restrict__ outf,
    const float* __restrict__ bias0, const float* __restrict__ bias1,
    const float* __restrict__ bias2,
    float* __restrict__ rsum, int bh_base, int ktiles)
{
    constexpr int LDA = (MODE == 2) ? 2048 : (MODE == 3) ? 4096 : 512;
    constexpr int LDB = (MODE == 2) ? 2048 : (MODE == 3) ? 4096 : 512;

    __shared__ u16 lsA[128][64];       // 16 KiB
    __shared__ u16 lsB[128][64];       // 16 KiB

    const int tid = threadIdx.x;
    const int bx = blockIdx.x, by = blockIdx.y, bz = blockIdx.z;

    const u16* A; const u16* Bt;
    if constexpr (MODE == 0) {
        A  = Abase + (size_t)bz * 2097152 + (size_t)by * 128 * 512;
        Bt = Bbase + (size_t)bz * 2097152 + (size_t)bx * 128 * 512;
    } else if constexpr (MODE == 1) {
        int bh = bh_base + bz;
        A  = Abase + (size_t)bh * 1048576 + (size_t)by * 128 * 512;
        Bt = Bbase + (size_t)bh * 1048576 + (size_t)bx * 128 * 512;
    } else if constexpr (MODE == 2) {
        int bh = bh_base + bz;
        A  = Abase + (size_t)bz * 4194304 + (size_t)by * 128 * 2048;
        Bt = Bbase + (size_t)bh * 1048576 + (size_t)bx * 128 * 2048;
    } else {
        A  = Abase + (size_t)by * 128 * 4096 + (size_t)bz * (ktiles * 64);
        Bt = Bbase + (size_t)bx * 128 * 4096 + (size_t)bz * (ktiles * 64);
    }

    const int l  = tid & 63, w = tid >> 6;
    const int wm = (w >> 1) * 64, wn = (w & 1) * 64;         // wave tile origin
    const int lg = l >> 4, lr = l & 15;
    const int swz = (lr & 7) << 4;

    f32x4 acc[4][4];
    #pragma unroll
    for (int m = 0; m < 4; ++m)
        #pragma unroll
        for (int n = 0; n < 4; ++n)
            #pragma unroll
            for (int r = 0; r < 4; ++r) acc[m][n][r] = 0.f;

    for (int t = 0; t < ktiles; ++t) {
        const int koff = t * 64;
        // ---- stage tile t (linear LDS dest, inverse-swizzled global source) ----
        #pragma unroll
        for (int i = 0; i < 4; ++i) {
            const int a   = (i * 256 + tid) * 16;            // linear byte in 16KB region
            const int row = a >> 7;                          // 0..127
            const int cb  = (a & 127) ^ ((row & 7) << 4);    // logical byte-in-row
            const u16* ga = A  + (size_t)row * LDA + koff + (cb >> 1);
            const u16* gb = Bt + (size_t)row * LDB + koff + (cb >> 1);
            lds_u32* la = (lds_u32*)((char*)&lsA[0][0] + i * 4096 + (w << 10));
            lds_u32* lb = (lds_u32*)((char*)&lsB[0][0] + i * 4096 + (w << 10));
            __builtin_amdgcn_global_load_lds((gbl_u32*)ga, la, 16, 0, 0);
            __builtin_amdgcn_global_load_lds((gbl_u32*)gb, lb, 16, 0, 0);
        }
        __syncthreads();                                     // drains vmcnt; tile resident

        // ---- compute: 2 k-slices x 16 MFMA ----
        #pragma unroll
        for (int ks = 0; ks < 2; ++ks) {
            s16x8 av[4], bv[4];
            #pragma unroll
            for (int m = 0; m < 4; ++m) {
                const int row = wm + m * 16 + lr;
                av[m] = *(const s16x8*)((const char*)&lsA[0][0] + row * 128 + ((ks * 64 + lg * 16) ^ swz));
            }
            #pragma unroll
            for (int n = 0; n < 4; ++n) {
                const int row = wn + n * 16 + lr;
                bv[n] = *(const s16x8*)((const char*)&lsB[0][0] + row * 128 + ((ks * 64 + lg * 16) ^ swz));
            }
            #pragma unroll
            for (int m = 0; m < 4; ++m)
                #pragma unroll
                for (int n = 0; n < 4; ++n)
                    acc[m][n] = __builtin_amdgcn_mfma_f32_16x16x32_bf16(av[m], bv[n], acc[m][n], 0, 0, 0);
        }
        __syncthreads();                                     // all reads done before next stage
    }

    // ---------------- epilogue: C/D col = lr, row = lg*4 + r  [m89 verified] ----------------
    if constexpr (MODE == 0) {
        const float* bias = (bz == 0) ? bias0 : ((bz == 1) ? bias1 : bias2);
        #pragma unroll
        for (int m = 0; m < 4; ++m)
        #pragma unroll
        for (int n = 0; n < 4; ++n)
        #pragma unroll
        for (int r = 0; r < 4; ++r) {
            const int grow = by * 128 + wm + m * 16 + lg * 4 + r;   // b*2048+s
            const int gcol = bx * 128 + wn + n * 16 + lr;           // h*512+d
            const u16 o = f2bf(acc[m][n][r] + bias[gcol]);
            const int bb = grow >> 11, ss = grow & 2047;
            const int hh = gcol >> 9,  dd = gcol & 511;
            if (bz == 0)      out0[(((size_t)(bb * 8 + hh) * 2048 + ss) << 9)  + dd] = o;
            else if (bz == 1) out1[(((size_t)(bb * 8 + hh) * 2048 + ss) << 9)  + dd] = o;
            else              out2[(((size_t)(bb * 8 + hh) * 512  + dd) << 11) + ss] = o; // v^T
        }
    } else if constexpr (MODE == 1) {
        const int bh = bh_base + bz;
        u16* Pp = out0 + (size_t)bz * 4194304;
        #pragma unroll
        for (int m = 0; m < 4; ++m)
        #pragma unroll
        for (int r = 0; r < 4; ++r) {
            const int grow = by * 128 + wm + m * 16 + lg * 4 + r;
            float rs = 0.f;
            #pragma unroll
            for (int n = 0; n < 4; ++n) {
                const int gcol = bx * 128 + wn + n * 16 + lr;
                float p = __expf(acc[m][n][r] * 0.04419417382415922f);  // 1/sqrt(512)
                rs += p;
                Pp[((size_t)grow << 11) + gcol] = f2bf(p);
            }
            #pragma unroll
            for (int o = 1; o < 16; o <<= 1) rs += __shfl_xor(rs, o, 64);
            if (lr == 0) atomicAdd(&rsum[bh * 2048 + grow], rs);
        }
    } else if constexpr (MODE == 2) {
        const int bh = bh_base + bz;
        const int bb = bh >> 3, hh = bh & 7;
        #pragma unroll
        for (int m = 0; m < 4; ++m)
        #pragma unroll
        for (int r = 0; r < 4; ++r) {
            const int grow = by * 128 + wm + m * 16 + lg * 4 + r;
            const float ri = 1.0f / rsum[bh * 2048 + grow];
            #pragma unroll
            for (int n = 0; n < 4; ++n) {
                const int gcol = bx * 128 + wn + n * 16 + lr;           // 0..511
                out0[((size_t)(bb * 2048 + grow) << 12) + hh * 512 + gcol] = f2bf(acc[m][n][r] * ri);
            }
        }
    } else {
        #pragma unroll
        for (int m = 0; m < 4; ++m)
        #pragma unroll
        for (int n = 0; n < 4; ++n)
        #pragma unroll
        for (int r = 0; r < 4; ++r) {
            const int grow = by * 128 + wm + m * 16 + lg * 4 + r;       // 0..4095
            const int gcol = bx * 128 + wn + n * 16 + lr;               // 0..511
            outf[(size_t)bz * 2097152 + (size_t)grow * 512 + gcol] = acc[m][n][r];
        }
    }
}

extern "C" void kernel_launch(void* const* d_in, const int* in_sizes, int n_in,
                              void* d_out, int out_size, void* d_ws, size_t ws_size,
                              hipStream_t stream) {
    const float* Q  = (const float*)d_in[0];
    const float* K  = (const float*)d_in[1];
    const float* V  = (const float*)d_in[2];
    const float* bq = (const float*)d_in[4];
    const float* bk = (const float*)d_in[6];
    const float* bv = (const float*)d_in[8];
    const float* bo = (const float*)d_in[10];
    const float* Wq = (const float*)d_in[3];
    const float* Wk = (const float*)d_in[5];
    const float* Wv = (const float*)d_in[7];
    const float* Wo = (const float*)d_in[9];
    float* out = (float*)d_out;

    char* ws = (char*)d_ws;
    u16*   qkvbf = (u16*)  (ws + 0);            // [3][4096][512] bf16
    u16*   Wt    = (u16*)  (ws + 12582912);     // Wq^T,Wk^T,Wv^T [3][4096][512]
    u16*   WoT   = (u16*)  (ws + 25165824);     // Wo^T [512][4096]
    float* rsum  = (float*)(ws + 29360128);     // [16][2048]
    u16*   qproj = (u16*)  (ws + 29491200);     // [B,H,S,512]
    u16*   kproj = (u16*)  (ws + 63045632);     // [B,H,S,512]
    u16*   vT    = (u16*)  (ws + 96600064);     // [B,H,512,S]
    u16*   Oattn = (u16*)  (ws + 130154496);    // [B*S][4096]
    u16*   P     = (u16*)  (ws + 163708928);    // chunked [ch][2048][2048]
    float* part  = (float*)(ws + 163708928);    // reused: [splitk][4096][512] f32

    size_t avail = (ws_size > (size_t)163708928) ? ws_size - (size_t)163708928 : 0;
    int hp = (int)(avail / 8388608);
    if (hp < 1)  hp = 1;
    if (hp > 16) hp = 16;
    int splitk = (hp >= 8) ? 8 : (hp >= 4) ? 4 : (hp >= 2) ? 2 : 1;

    // input converts
    k_cvt<<<2048, 256, 0, stream>>>(Q, qkvbf,            524288);
    k_cvt<<<2048, 256, 0, stream>>>(K, qkvbf + 2097152,  524288);
    k_cvt<<<2048, 256, 0, stream>>>(V, qkvbf + 4194304,  524288);
    dim3 tb(32, 8);
    k_tcvt<<<dim3(128, 16), tb, 0, stream>>>(Wq, Wt,            512, 4096);
    k_tcvt<<<dim3(128, 16), tb, 0, stream>>>(Wk, Wt + 2097152,  512, 4096);
    k_tcvt<<<dim3(128, 16), tb, 0, stream>>>(Wv, Wt + 4194304,  512, 4096);
    k_tcvt<<<dim3(16, 128), tb, 0, stream>>>(Wo, WoT,           4096, 512);
    k_zero<<<128, 256, 0, stream>>>(rsum, 32768);

    // fused QKV projections (+bias): q,k -> [B,H,S,D], v -> [B,H,D,S]
    k_gemm<0><<<dim3(32, 32, 3), 256, 0, stream>>>(qkvbf, Wt, qproj, kproj, vT, nullptr,
                                                   bq, bk, bv, nullptr, 0, 8);

    // attention: P = exp(qk^T*scale) with fused row-sums; O = P v / rowsum
    for (int h0 = 0; h0 < 16; h0 += hp) {
        int ch = (16 - h0 < hp) ? (16 - h0) : hp;
        k_gemm<1><<<dim3(16, 16, ch), 256, 0, stream>>>(qproj, kproj, P, nullptr, nullptr,
                                                        nullptr, nullptr, nullptr, nullptr,
                                                        rsum, h0, 8);
        k_gemm<2><<<dim3(4, 16, ch), 256, 0, stream>>>(P, vT, Oattn, nullptr, nullptr,
                                                       nullptr, nullptr, nullptr, nullptr,
                                                       rsum, h0, 32);
    }

    // final projection: split-K partials + reduce(+bias) -> f32 out
    k_gemm<3><<<dim3(4, 32, splitk), 256, 0, stream>>>(Oattn, WoT, nullptr, nullptr, nullptr,
                                                       part, nullptr, nullptr, nullptr,
                                                       nullptr, 0, 512 / (64 * splitk) * 8);
    k_reduce<<<2048, 256, 0, stream>>>(part, bo, out, splitk);
}